// Round 1
// baseline (526.119 us; speedup 1.0000x reference)
//
#include <hip/hip_runtime.h>
#include <math.h>

#define FINF 3.0e38f

__device__ __forceinline__ unsigned mapf(float f) {
  unsigned u = __float_as_uint(f);
  return (u & 0x80000000u) ? ~u : (u | 0x80000000u);
}
__device__ __forceinline__ float unmapf(unsigned u) {
  unsigned b = (u & 0x80000000u) ? (u ^ 0x80000000u) : ~u;
  return __uint_as_float(b);
}

// ---------------- init small scratch ----------------
__global__ void k_init(unsigned* __restrict__ hist, int* __restrict__ cnt,
                       unsigned* __restrict__ mm) {
  int i = blockIdx.x * 256 + threadIdx.x;
  if (i < 16 * 4096) hist[i] = 0u;
  if (i < 16) cnt[i] = 0;
  if (i == 0) { mm[0] = 0xFFFFFFFFu; mm[1] = 0u; }
}

// ---------------- conv1: latent(16,256,32,32) * W1(128,256,3,3) s2 p1 -> partials ----------------
// grid (16 batch, 16 ocg, 2 ksplit), block 256 (one output pixel each), 8 oc per thread
__global__ __launch_bounds__(256) void k_conv1(const float* __restrict__ lat,
                                               const float* __restrict__ w1,
                                               float* __restrict__ h1part) {
  const int b = blockIdx.x;
  const int ocg = blockIdx.y;
  const int ks = blockIdx.z;
  const int t = threadIdx.x;
  const int oy = t >> 4, ox = t & 15;
  __shared__ float4 sIn4[2048];  // 8 channels x 32x32
  float* sIn = (float*)sIn4;
  float acc[8];
#pragma unroll
  for (int j = 0; j < 8; ++j) acc[j] = 0.f;
  const int ocb = ocg * 8;
#pragma unroll 1
  for (int cc = 0; cc < 16; ++cc) {
    const int icc = ks * 128 + cc * 8;
    const float4* src = (const float4*)(lat + ((size_t)b * 256 + icc) * 1024);
    __syncthreads();
#pragma unroll
    for (int j = 0; j < 8; ++j) sIn4[t + j * 256] = src[t + j * 256];
    __syncthreads();
#pragma unroll 1
    for (int ic = 0; ic < 8; ++ic) {
      const float* ib = sIn + ic * 1024;
#pragma unroll
      for (int ky = 0; ky < 3; ++ky) {
        const int iy = 2 * oy - 1 + ky;
        if (iy < 0) continue;
#pragma unroll
        for (int kx = 0; kx < 3; ++kx) {
          const int ix = 2 * ox - 1 + kx;
          if (ix < 0) continue;
          const float v = ib[iy * 32 + ix];
          const int tap = ky * 3 + kx;
#pragma unroll
          for (int j = 0; j < 8; ++j) {
            // weight index is block-uniform -> scalar loads
            acc[j] = fmaf(w1[((size_t)(ocb + j) * 256 + (icc + ic)) * 9 + tap], v, acc[j]);
          }
        }
      }
    }
  }
  float* dst = h1part + (size_t)ks * 524288 + ((size_t)b * 128 + ocb) * 256 + t;
#pragma unroll
  for (int j = 0; j < 8; ++j) dst[j * 256] = acc[j];
}

// ---------------- combine ksplit partials + bias + leaky ----------------
__global__ void k_combine(float* __restrict__ h1a, const float* __restrict__ h1b,
                          const float* __restrict__ b1) {
  const int i = blockIdx.x * 256 + threadIdx.x;  // float4 index, 131072 total
  float4 a = ((const float4*)h1a)[i];
  const float4 q = ((const float4*)h1b)[i];
  const int oc = (i >> 6) & 127;
  const float bias = b1[oc];
  float s;
  s = a.x + q.x + bias; a.x = s >= 0.f ? s : 0.02f * s;
  s = a.y + q.y + bias; a.y = s >= 0.f ? s : 0.02f * s;
  s = a.z + q.z + bias; a.z = s >= 0.f ? s : 0.02f * s;
  s = a.w + q.w + bias; a.w = s >= 0.f ? s : 0.02f * s;
  ((float4*)h1a)[i] = a;
}

// ---------------- conv2 + mean + 1x1 conv + tanh -> params[b] ----------------
__global__ __launch_bounds__(256) void k_conv2(const float* __restrict__ h1,
                                               const float* __restrict__ w2,
                                               const float* __restrict__ b2,
                                               const float* __restrict__ w3,
                                               const float* __restrict__ b3,
                                               float* __restrict__ params) {
  const int b = blockIdx.x;
  const int t = threadIdx.x;
  __shared__ float sW[1152];
  __shared__ float red[256];
  for (int i = t; i < 1152; i += 256) sW[i] = w2[i];
  __syncthreads();
  const int pix = t >> 2, icq = t & 3;
  const int oy = pix >> 3, ox = pix & 7;
  const float* hb = h1 + (size_t)b * 128 * 256;
  float s = 0.f;
  for (int ic = icq * 32; ic < icq * 32 + 32; ++ic) {
    const float* hp = hb + ic * 256;
#pragma unroll
    for (int ky = 0; ky < 3; ++ky) {
      const int iy = 2 * oy - 1 + ky;
      if (iy < 0) continue;
#pragma unroll
      for (int kx = 0; kx < 3; ++kx) {
        const int ix = 2 * ox - 1 + kx;
        if (ix < 0) continue;
        s += sW[ic * 9 + ky * 3 + kx] * hp[iy * 16 + ix];
      }
    }
  }
  red[t] = s;
  __syncthreads();
  for (int off = 128; off > 0; off >>= 1) {
    if (t < off) red[t] += red[t + off];
    __syncthreads();
  }
  if (t == 0) {
    const float mean = red[0] / 64.f + b2[0];
    const float h = w3[0] * mean + b3[0];
    params[b] = tanhf(h) * 0.5f + 0.5f;
  }
}

// ---------------- histogram of dark channel ----------------
__global__ __launch_bounds__(256) void k_hist(const float* __restrict__ x,
                                              unsigned* __restrict__ ghist) {
  const int b = blockIdx.y, blk = blockIdx.x, t = threadIdx.x;
  __shared__ unsigned lh[4096];
  for (int i = t; i < 4096; i += 256) lh[i] = 0u;
  __syncthreads();
  const float* xr = x + (size_t)b * 3 * 262144;
  const float* xg = xr + 262144;
  const float* xb = xg + 262144;
  const int f0 = blk * 2048;
#pragma unroll
  for (int i = 0; i < 8; ++i) {
    const int f4 = f0 + t + i * 256;
    const float4 r = ((const float4*)xr)[f4];
    const float4 g = ((const float4*)xg)[f4];
    const float4 bl = ((const float4*)xb)[f4];
    float d;
    d = fminf(fminf(r.x, g.x), bl.x); atomicAdd(&lh[min(4095, (int)(d * 4096.f))], 1u);
    d = fminf(fminf(r.y, g.y), bl.y); atomicAdd(&lh[min(4095, (int)(d * 4096.f))], 1u);
    d = fminf(fminf(r.z, g.z), bl.z); atomicAdd(&lh[min(4095, (int)(d * 4096.f))], 1u);
    d = fminf(fminf(r.w, g.w), bl.w); atomicAdd(&lh[min(4095, (int)(d * 4096.f))], 1u);
  }
  __syncthreads();
  for (int i = t; i < 4096; i += 256)
    if (lh[i]) atomicAdd(&ghist[b * 4096 + i], lh[i]);
}

// ---------------- suffix scan from top to find threshold bin ----------------
__global__ __launch_bounds__(256) void k_scan(const unsigned* __restrict__ ghist,
                                              int* __restrict__ Bbin, int* __restrict__ rneed) {
  const int b = blockIdx.x, t = threadIdx.x;
  __shared__ unsigned h[4096];
  __shared__ unsigned csum[256];
  for (int i = t; i < 4096; i += 256) h[i] = ghist[b * 4096 + i];
  __syncthreads();
  const int top = 4095 - 16 * t;
  unsigned s = 0;
#pragma unroll
  for (int k = 0; k < 16; ++k) s += h[top - k];
  csum[t] = s;
  __syncthreads();
  for (int off = 1; off < 256; off <<= 1) {
    const unsigned add = (t >= off) ? csum[t - off] : 0u;
    __syncthreads();
    csum[t] += add;
    __syncthreads();
  }
  const unsigned incl = csum[t];
  const unsigned before = incl - s;
  if (before < 262u && incl >= 262u) {
    unsigned cum = before;
    for (int k = 0; k < 16; ++k) {
      const unsigned c = h[top - k];
      if (cum + c >= 262u) { Bbin[b] = top - k; rneed[b] = (int)(262u - cum); break; }
      cum += c;
    }
  }
}

// ---------------- collect: sums above threshold bin + boundary candidates ----------------
__global__ __launch_bounds__(256) void k_collect(const float* __restrict__ x,
                                                 const int* __restrict__ Bbin,
                                                 int* __restrict__ cnt,
                                                 float* __restrict__ candv,
                                                 int* __restrict__ candi,
                                                 float* __restrict__ bsums) {
  const int b = blockIdx.y, blk = blockIdx.x, t = threadIdx.x;
  const int B = Bbin[b];
  const float* xr = x + (size_t)b * 3 * 262144;
  const float* xg = xr + 262144;
  const float* xb = xg + 262144;
  const int f0 = blk * 2048;
  float s0 = 0.f, s1 = 0.f, s2 = 0.f;
#pragma unroll
  for (int i = 0; i < 8; ++i) {
    const int f4 = f0 + t + i * 256;
    const float4 r = ((const float4*)xr)[f4];
    const float4 g = ((const float4*)xg)[f4];
    const float4 bl = ((const float4*)xb)[f4];
    const float rv[4] = {r.x, r.y, r.z, r.w};
    const float gv[4] = {g.x, g.y, g.z, g.w};
    const float bv[4] = {bl.x, bl.y, bl.z, bl.w};
#pragma unroll
    for (int j = 0; j < 4; ++j) {
      const float d = fminf(fminf(rv[j], gv[j]), bv[j]);
      const int bin = min(4095, (int)(d * 4096.f));
      if (bin > B) {
        s0 += rv[j]; s1 += gv[j]; s2 += bv[j];
      } else if (bin == B) {
        const int k = atomicAdd(&cnt[b], 1);
        if (k < 4096) { candv[b * 4096 + k] = d; candi[b * 4096 + k] = f4 * 4 + j; }
      }
    }
  }
  __shared__ float red[256];
  red[t] = s0; __syncthreads();
  for (int off = 128; off > 0; off >>= 1) { if (t < off) red[t] += red[t + off]; __syncthreads(); }
  if (t == 0) bsums[((size_t)b * 32 + blk) * 3 + 0] = red[0];
  __syncthreads();
  red[t] = s1; __syncthreads();
  for (int off = 128; off > 0; off >>= 1) { if (t < off) red[t] += red[t + off]; __syncthreads(); }
  if (t == 0) bsums[((size_t)b * 32 + blk) * 3 + 1] = red[0];
  __syncthreads();
  red[t] = s2; __syncthreads();
  for (int off = 128; off > 0; off >>= 1) { if (t < off) red[t] += red[t + off]; __syncthreads(); }
  if (t == 0) bsums[((size_t)b * 32 + blk) * 3 + 2] = red[0];
}

// ---------------- finalize A (deterministic; tie-break value desc, index asc) ----------------
__global__ void k_finalA(const float* __restrict__ x, const float* __restrict__ bsums,
                         const int* __restrict__ cnt, const int* __restrict__ rneed,
                         float* __restrict__ candv, const int* __restrict__ candi,
                         float* __restrict__ Av, float* __restrict__ invA) {
  const int b = blockIdx.x;
  if (threadIdx.x != 0) return;
  float S0 = 0.f, S1 = 0.f, S2 = 0.f;
  for (int k = 0; k < 32; ++k) {
    S0 += bsums[((size_t)b * 32 + k) * 3 + 0];
    S1 += bsums[((size_t)b * 32 + k) * 3 + 1];
    S2 += bsums[((size_t)b * 32 + k) * 3 + 2];
  }
  const int n = min(cnt[b], 4096);
  const int r = rneed[b];
  const float* xr = x + (size_t)b * 3 * 262144;
  const float* xg = xr + 262144;
  const float* xb = xg + 262144;
  for (int sel = 0; sel < r; ++sel) {
    int best = -1; float bv = -1.f; int bi = 0x7FFFFFFF;
    for (int i = 0; i < n; ++i) {
      const float v = candv[b * 4096 + i];
      const int id = candi[b * 4096 + i];
      if (v > bv || (v == bv && id < bi)) { best = i; bv = v; bi = id; }
    }
    if (best < 0) break;
    candv[b * 4096 + best] = -1.f;
    S0 += xr[bi]; S1 += xg[bi]; S2 += xb[bi];
  }
  const float a0 = S0 / 262.f, a1 = S1 / 262.f, a2 = S2 / 262.f;
  Av[b * 3 + 0] = a0; Av[b * 3 + 1] = a1; Av[b * 3 + 2] = a2;
  invA[b * 3 + 0] = 1.f / a0; invA[b * 3 + 1] = 1.f / a1; invA[b * 3 + 2] = 1.f / a2;
}

// ---------------- dc2 + horizontal 7-min ----------------
__global__ __launch_bounds__(256) void k_dch(const float* __restrict__ x,
                                             const float* __restrict__ Av,
                                             float* __restrict__ dcH) {
  const int y = blockIdx.x, b = blockIdx.y, t = threadIdx.x;
  __shared__ float srow[518];
  const float a0 = Av[b * 3 + 0], a1 = Av[b * 3 + 1], a2 = Av[b * 3 + 2];
  const size_t rowoff = (size_t)b * 3 * 262144 + (size_t)y * 512;
  const float* xr = x + rowoff;
  const float* xg = xr + 262144;
  const float* xb = xg + 262144;
  const float2 r = ((const float2*)xr)[t];
  const float2 g = ((const float2*)xg)[t];
  const float2 bl = ((const float2*)xb)[t];
  srow[3 + 2 * t + 0] = fminf(fminf(r.x / a0, g.x / a1), bl.x / a2);
  srow[3 + 2 * t + 1] = fminf(fminf(r.y / a0, g.y / a1), bl.y / a2);
  if (t < 3) { srow[t] = FINF; srow[515 + t] = FINF; }
  __syncthreads();
  float2 o;
  float m = srow[2 * t];
#pragma unroll
  for (int k = 1; k < 7; ++k) m = fminf(m, srow[2 * t + k]);
  o.x = m;
  m = srow[2 * t + 1];
#pragma unroll
  for (int k = 1; k < 7; ++k) m = fminf(m, srow[2 * t + 1 + k]);
  o.y = m;
  ((float2*)(dcH + ((size_t)b * 512 + y) * 512))[t] = o;
}

// ---------------- final: vertical 7-min + transmission + dehaze + global min/max ----------------
__global__ __launch_bounds__(256) void k_final(const float* __restrict__ x,
                                               const float* __restrict__ dcH,
                                               const float* __restrict__ params,
                                               const float* __restrict__ Av,
                                               float* __restrict__ out,
                                               unsigned* __restrict__ mm) {
  const int y = blockIdx.x, b = blockIdx.y, t = threadIdx.x;
  const float pb = params[b];
  const float a0 = Av[b * 3 + 0], a1 = Av[b * 3 + 1], a2 = Av[b * 3 + 2];
  const float* dH = dcH + (size_t)b * 262144;
  float2 vm = make_float2(FINF, FINF);
#pragma unroll
  for (int dy = -3; dy <= 3; ++dy) {
    const int yy = y + dy;
    if (yy < 0 || yy > 511) continue;
    const float2 v = ((const float2*)(dH + (size_t)yy * 512))[t];
    vm.x = fminf(vm.x, v.x);
    vm.y = fminf(vm.y, v.y);
  }
  const float T0 = fmaxf(1.f - pb * vm.x, 0.01f);
  const float T1 = fmaxf(1.f - pb * vm.y, 0.01f);
  const size_t rowoff = (size_t)b * 3 * 262144 + (size_t)y * 512;
  float lmin = FINF, lmax = -FINF;
#pragma unroll
  for (int c = 0; c < 3; ++c) {
    const float a = (c == 0) ? a0 : ((c == 1) ? a1 : a2);
    const float2 xv = ((const float2*)(x + rowoff + (size_t)c * 262144))[t];
    const float o0 = (xv.x - a) / T0 + a;
    const float o1 = (xv.y - a) / T1 + a;
    lmin = fminf(lmin, fminf(o0, o1));
    lmax = fmaxf(lmax, fmaxf(o0, o1));
    ((float2*)(out + rowoff + (size_t)c * 262144))[t] = make_float2(o0, o1);
  }
  __shared__ float red[256];
  red[t] = lmin; __syncthreads();
  for (int off = 128; off > 0; off >>= 1) { if (t < off) red[t] = fminf(red[t], red[t + off]); __syncthreads(); }
  if (t == 0) atomicMin(&mm[0], mapf(red[0]));
  __syncthreads();
  red[t] = lmax; __syncthreads();
  for (int off = 128; off > 0; off >>= 1) { if (t < off) red[t] = fmaxf(red[t], red[t + off]); __syncthreads(); }
  if (t == 0) atomicMax(&mm[1], mapf(red[0]));
}

// ---------------- global normalize ----------------
__global__ void k_norm(float* __restrict__ out, const unsigned* __restrict__ mm) {
  const float mn = unmapf(mm[0]);
  const float mx = unmapf(mm[1]);
  const float sc = 1.f / (mx - mn);
  const int total4 = 16 * 3 * 262144 / 4;
  for (int i = blockIdx.x * 256 + threadIdx.x; i < total4; i += gridDim.x * 256) {
    float4 v = ((float4*)out)[i];
    v.x = (v.x - mn) * sc;
    v.y = (v.y - mn) * sc;
    v.z = (v.z - mn) * sc;
    v.w = (v.w - mn) * sc;
    ((float4*)out)[i] = v;
  }
}

extern "C" void kernel_launch(void* const* d_in, const int* in_sizes, int n_in,
                              void* d_out, int out_size, void* d_ws, size_t ws_size,
                              hipStream_t stream) {
  const float* x   = (const float*)d_in[0];
  const float* lat = (const float*)d_in[1];
  const float* w1  = (const float*)d_in[2];
  const float* b1  = (const float*)d_in[3];
  const float* w2  = (const float*)d_in[4];
  const float* b2  = (const float*)d_in[5];
  const float* w3  = (const float*)d_in[6];
  const float* b3  = (const float*)d_in[7];
  float* out = (float*)d_out;

  char* ws = (char*)d_ws;
  size_t off = 0;
  auto alloc = [&](size_t sz) -> void* {
    off = (off + 255) & ~(size_t)255;
    void* p = ws + off;
    off += sz;
    return p;
  };
  float*    h1p   = (float*)alloc(2 * 524288 * sizeof(float));  // two ksplit partials
  float*    paramsp = (float*)alloc(16 * sizeof(float));
  unsigned* hist  = (unsigned*)alloc(16 * 4096 * sizeof(unsigned));
  int*      Bbin  = (int*)alloc(16 * sizeof(int));
  int*      rneed = (int*)alloc(16 * sizeof(int));
  int*      cnt   = (int*)alloc(16 * sizeof(int));
  float*    bsums = (float*)alloc(16 * 32 * 3 * sizeof(float));
  float*    candv = (float*)alloc(16 * 4096 * sizeof(float));
  int*      candi = (int*)alloc(16 * 4096 * sizeof(int));
  float*    Av    = (float*)alloc(16 * 3 * sizeof(float));
  float*    invA  = (float*)alloc(16 * 3 * sizeof(float));
  unsigned* mm    = (unsigned*)alloc(2 * sizeof(unsigned));
  float*    dcH   = (float*)alloc((size_t)16 * 512 * 512 * sizeof(float));  // ~22 MB total

  k_init<<<256, 256, 0, stream>>>(hist, cnt, mm);
  k_conv1<<<dim3(16, 16, 2), 256, 0, stream>>>(lat, w1, h1p);
  k_combine<<<512, 256, 0, stream>>>(h1p, h1p + 524288, b1);
  k_conv2<<<16, 256, 0, stream>>>(h1p, w2, b2, w3, b3, paramsp);
  k_hist<<<dim3(32, 16), 256, 0, stream>>>(x, hist);
  k_scan<<<16, 256, 0, stream>>>(hist, Bbin, rneed);
  k_collect<<<dim3(32, 16), 256, 0, stream>>>(x, Bbin, cnt, candv, candi, bsums);
  k_finalA<<<16, 64, 0, stream>>>(x, bsums, cnt, rneed, candv, candi, Av, invA);
  k_dch<<<dim3(512, 16), 256, 0, stream>>>(x, Av, dcH);
  k_final<<<dim3(512, 16), 256, 0, stream>>>(x, dcH, paramsp, Av, out, mm);
  k_norm<<<4096, 256, 0, stream>>>(out, mm);
}

// Round 2
// 368.512 us; speedup vs baseline: 1.4277x; 1.4277x over previous
//
#include <hip/hip_runtime.h>
#include <math.h>

#define FINF 3.0e38f

__device__ __forceinline__ unsigned mapf(float f) {
  unsigned u = __float_as_uint(f);
  return (u & 0x80000000u) ? ~u : (u | 0x80000000u);
}
__device__ __forceinline__ float unmapf(unsigned u) {
  unsigned b = (u & 0x80000000u) ? (u ^ 0x80000000u) : ~u;
  return __uint_as_float(b);
}

// ---------------- init small scratch ----------------
__global__ void k_init(unsigned* __restrict__ hist, int* __restrict__ cnt,
                       unsigned* __restrict__ mm) {
  int i = blockIdx.x * 256 + threadIdx.x;
  if (i < 16 * 4096) hist[i] = 0u;
  if (i < 16) cnt[i] = 0;
  if (i == 0) { mm[0] = 0xFFFFFFFFu; mm[1] = 0u; }
}

// ---------------- transpose W1 (128,256,3,3) -> wt[ic][tap][oc] ----------------
__global__ void k_wt(const float* __restrict__ w1, float* __restrict__ wt) {
  const int idx = blockIdx.x * 256 + threadIdx.x;  // 294912 = 256*9*128
  if (idx >= 294912) return;
  const int oc = idx & 127;
  const int r = idx >> 7;
  const int tap = r % 9;
  const int ic = r / 9;
  wt[idx] = w1[((size_t)oc * 256 + ic) * 9 + tap];
}

// ---------------- conv1: latent(16,256,32,32) * W1 s2 p1 -> 8 ksplit partials ----------------
// grid (16 b, 16 ocg, 8 ks), block 256 (one output pixel each), 8 oc per thread, 32 ic per block
__global__ __launch_bounds__(256) void k_conv1(const float* __restrict__ lat,
                                               const float* __restrict__ wt,
                                               float* __restrict__ h1part) {
  const int b = blockIdx.x;
  const int ocg = blockIdx.y;
  const int ks = blockIdx.z;
  const int t = threadIdx.x;
  const int oy = t >> 4, ox = t & 15;
  __shared__ float sIn[4 * 1024];  // 4 channels x 32x32 = 16 KB
  float acc[8];
#pragma unroll
  for (int j = 0; j < 8; ++j) acc[j] = 0.f;
  const int ocb = ocg * 8;
  const int icb = ks * 32;
#pragma unroll 1
  for (int cc = 0; cc < 8; ++cc) {
    const int ic0 = icb + cc * 4;
    const float4* src = (const float4*)lat + ((size_t)b * 256 + ic0) * 256;
    __syncthreads();
#pragma unroll
    for (int ch = 0; ch < 4; ++ch) ((float4*)sIn)[ch * 256 + t] = src[ch * 256 + t];
    __syncthreads();
#pragma unroll
    for (int ic = 0; ic < 4; ++ic) {
      const float* ib = sIn + ic * 1024;
      const float* wp = wt + (size_t)(ic0 + ic) * 9 * 128 + ocb;
#pragma unroll
      for (int ky = 0; ky < 3; ++ky) {
        const int iy = 2 * oy - 1 + ky;
        if (iy < 0) continue;
#pragma unroll
        for (int kx = 0; kx < 3; ++kx) {
          const int ix = 2 * ox - 1 + kx;
          if (ix < 0) continue;
          const float v = ib[iy * 32 + ix];
          const float* w8 = wp + (ky * 3 + kx) * 128;
          const float4 wa = *(const float4*)(w8);
          const float4 wb = *(const float4*)(w8 + 4);
          acc[0] = fmaf(wa.x, v, acc[0]);
          acc[1] = fmaf(wa.y, v, acc[1]);
          acc[2] = fmaf(wa.z, v, acc[2]);
          acc[3] = fmaf(wa.w, v, acc[3]);
          acc[4] = fmaf(wb.x, v, acc[4]);
          acc[5] = fmaf(wb.y, v, acc[5]);
          acc[6] = fmaf(wb.z, v, acc[6]);
          acc[7] = fmaf(wb.w, v, acc[7]);
        }
      }
    }
  }
  float* dst = h1part + (size_t)ks * 524288 + ((size_t)b * 128 + ocb) * 256 + t;
#pragma unroll
  for (int j = 0; j < 8; ++j) dst[j * 256] = acc[j];
}

// ---------------- combine 8 ksplit partials + bias + leaky ----------------
__global__ void k_combine(const float* __restrict__ h1p, float* __restrict__ h1,
                          const float* __restrict__ b1) {
  const int i = blockIdx.x * 256 + threadIdx.x;  // float4 index, 131072 total
  const float4* p = (const float4*)h1p;
  float4 a = p[i];
#pragma unroll
  for (int ks = 1; ks < 8; ++ks) {
    const float4 q = p[(size_t)ks * 131072 + i];
    a.x += q.x; a.y += q.y; a.z += q.z; a.w += q.w;
  }
  const int oc = (i >> 6) & 127;
  const float bias = b1[oc];
  float s;
  s = a.x + bias; a.x = s >= 0.f ? s : 0.02f * s;
  s = a.y + bias; a.y = s >= 0.f ? s : 0.02f * s;
  s = a.z + bias; a.z = s >= 0.f ? s : 0.02f * s;
  s = a.w + bias; a.w = s >= 0.f ? s : 0.02f * s;
  ((float4*)h1)[i] = a;
}

// ---------------- conv2 + mean + 1x1 conv + tanh -> params[b] ----------------
__global__ __launch_bounds__(256) void k_conv2(const float* __restrict__ h1,
                                               const float* __restrict__ w2,
                                               const float* __restrict__ b2,
                                               const float* __restrict__ w3,
                                               const float* __restrict__ b3,
                                               float* __restrict__ params) {
  const int b = blockIdx.x;
  const int t = threadIdx.x;
  __shared__ float sW[1152];
  __shared__ float red[256];
  for (int i = t; i < 1152; i += 256) sW[i] = w2[i];
  __syncthreads();
  const int pix = t >> 2, icq = t & 3;
  const int oy = pix >> 3, ox = pix & 7;
  const float* hb = h1 + (size_t)b * 128 * 256;
  float s = 0.f;
  for (int ic = icq * 32; ic < icq * 32 + 32; ++ic) {
    const float* hp = hb + ic * 256;
#pragma unroll
    for (int ky = 0; ky < 3; ++ky) {
      const int iy = 2 * oy - 1 + ky;
      if (iy < 0) continue;
#pragma unroll
      for (int kx = 0; kx < 3; ++kx) {
        const int ix = 2 * ox - 1 + kx;
        if (ix < 0) continue;
        s += sW[ic * 9 + ky * 3 + kx] * hp[iy * 16 + ix];
      }
    }
  }
  red[t] = s;
  __syncthreads();
  for (int off = 128; off > 0; off >>= 1) {
    if (t < off) red[t] += red[t + off];
    __syncthreads();
  }
  if (t == 0) {
    const float mean = red[0] / 64.f + b2[0];
    const float h = w3[0] * mean + b3[0];
    params[b] = tanhf(h) * 0.5f + 0.5f;
  }
}

// ---------------- histogram of dark channel ----------------
__global__ __launch_bounds__(256) void k_hist(const float* __restrict__ x,
                                              unsigned* __restrict__ ghist) {
  const int b = blockIdx.y, blk = blockIdx.x, t = threadIdx.x;
  __shared__ unsigned lh[4096];
  for (int i = t; i < 4096; i += 256) lh[i] = 0u;
  __syncthreads();
  const float* xr = x + (size_t)b * 3 * 262144;
  const float* xg = xr + 262144;
  const float* xb = xg + 262144;
  const int f0 = blk * 2048;
#pragma unroll
  for (int i = 0; i < 8; ++i) {
    const int f4 = f0 + t + i * 256;
    const float4 r = ((const float4*)xr)[f4];
    const float4 g = ((const float4*)xg)[f4];
    const float4 bl = ((const float4*)xb)[f4];
    float d;
    d = fminf(fminf(r.x, g.x), bl.x); atomicAdd(&lh[min(4095, (int)(d * 4096.f))], 1u);
    d = fminf(fminf(r.y, g.y), bl.y); atomicAdd(&lh[min(4095, (int)(d * 4096.f))], 1u);
    d = fminf(fminf(r.z, g.z), bl.z); atomicAdd(&lh[min(4095, (int)(d * 4096.f))], 1u);
    d = fminf(fminf(r.w, g.w), bl.w); atomicAdd(&lh[min(4095, (int)(d * 4096.f))], 1u);
  }
  __syncthreads();
  for (int i = t; i < 4096; i += 256)
    if (lh[i]) atomicAdd(&ghist[b * 4096 + i], lh[i]);
}

// ---------------- suffix scan from top to find threshold bin ----------------
__global__ __launch_bounds__(256) void k_scan(const unsigned* __restrict__ ghist,
                                              int* __restrict__ Bbin, int* __restrict__ rneed) {
  const int b = blockIdx.x, t = threadIdx.x;
  __shared__ unsigned h[4096];
  __shared__ unsigned csum[256];
  for (int i = t; i < 4096; i += 256) h[i] = ghist[b * 4096 + i];
  __syncthreads();
  const int top = 4095 - 16 * t;
  unsigned s = 0;
#pragma unroll
  for (int k = 0; k < 16; ++k) s += h[top - k];
  csum[t] = s;
  __syncthreads();
  for (int off = 1; off < 256; off <<= 1) {
    const unsigned add = (t >= off) ? csum[t - off] : 0u;
    __syncthreads();
    csum[t] += add;
    __syncthreads();
  }
  const unsigned incl = csum[t];
  const unsigned before = incl - s;
  if (before < 262u && incl >= 262u) {
    unsigned cum = before;
    for (int k = 0; k < 16; ++k) {
      const unsigned c = h[top - k];
      if (cum + c >= 262u) { Bbin[b] = top - k; rneed[b] = (int)(262u - cum); break; }
      cum += c;
    }
  }
}

// ---------------- collect: sums above threshold bin + boundary candidates ----------------
__global__ __launch_bounds__(256) void k_collect(const float* __restrict__ x,
                                                 const int* __restrict__ Bbin,
                                                 int* __restrict__ cnt,
                                                 float* __restrict__ candv,
                                                 int* __restrict__ candi,
                                                 float* __restrict__ bsums) {
  const int b = blockIdx.y, blk = blockIdx.x, t = threadIdx.x;
  const int B = Bbin[b];
  const float* xr = x + (size_t)b * 3 * 262144;
  const float* xg = xr + 262144;
  const float* xb = xg + 262144;
  const int f0 = blk * 2048;
  float s0 = 0.f, s1 = 0.f, s2 = 0.f;
#pragma unroll
  for (int i = 0; i < 8; ++i) {
    const int f4 = f0 + t + i * 256;
    const float4 r = ((const float4*)xr)[f4];
    const float4 g = ((const float4*)xg)[f4];
    const float4 bl = ((const float4*)xb)[f4];
    const float rv[4] = {r.x, r.y, r.z, r.w};
    const float gv[4] = {g.x, g.y, g.z, g.w};
    const float bv[4] = {bl.x, bl.y, bl.z, bl.w};
#pragma unroll
    for (int j = 0; j < 4; ++j) {
      const float d = fminf(fminf(rv[j], gv[j]), bv[j]);
      const int bin = min(4095, (int)(d * 4096.f));
      if (bin > B) {
        s0 += rv[j]; s1 += gv[j]; s2 += bv[j];
      } else if (bin == B) {
        const int k = atomicAdd(&cnt[b], 1);
        if (k < 4096) { candv[b * 4096 + k] = d; candi[b * 4096 + k] = f4 * 4 + j; }
      }
    }
  }
  __shared__ float red[256];
  red[t] = s0; __syncthreads();
  for (int off = 128; off > 0; off >>= 1) { if (t < off) red[t] += red[t + off]; __syncthreads(); }
  if (t == 0) bsums[((size_t)b * 32 + blk) * 3 + 0] = red[0];
  __syncthreads();
  red[t] = s1; __syncthreads();
  for (int off = 128; off > 0; off >>= 1) { if (t < off) red[t] += red[t + off]; __syncthreads(); }
  if (t == 0) bsums[((size_t)b * 32 + blk) * 3 + 1] = red[0];
  __syncthreads();
  red[t] = s2; __syncthreads();
  for (int off = 128; off > 0; off >>= 1) { if (t < off) red[t] += red[t + off]; __syncthreads(); }
  if (t == 0) bsums[((size_t)b * 32 + blk) * 3 + 2] = red[0];
}

// ---------------- finalize A (deterministic; tie-break value desc, index asc) ----------------
__global__ void k_finalA(const float* __restrict__ x, const float* __restrict__ bsums,
                         const int* __restrict__ cnt, const int* __restrict__ rneed,
                         float* __restrict__ candv, const int* __restrict__ candi,
                         float* __restrict__ Av) {
  const int b = blockIdx.x;
  if (threadIdx.x != 0) return;
  float S0 = 0.f, S1 = 0.f, S2 = 0.f;
  for (int k = 0; k < 32; ++k) {
    S0 += bsums[((size_t)b * 32 + k) * 3 + 0];
    S1 += bsums[((size_t)b * 32 + k) * 3 + 1];
    S2 += bsums[((size_t)b * 32 + k) * 3 + 2];
  }
  const int n = min(cnt[b], 4096);
  const int r = rneed[b];
  const float* xr = x + (size_t)b * 3 * 262144;
  const float* xg = xr + 262144;
  const float* xb = xg + 262144;
  for (int sel = 0; sel < r; ++sel) {
    int best = -1; float bv = -1.f; int bi = 0x7FFFFFFF;
    for (int i = 0; i < n; ++i) {
      const float v = candv[b * 4096 + i];
      const int id = candi[b * 4096 + i];
      if (v > bv || (v == bv && id < bi)) { best = i; bv = v; bi = id; }
    }
    if (best < 0) break;
    candv[b * 4096 + best] = -1.f;
    S0 += xr[bi]; S1 += xg[bi]; S2 += xb[bi];
  }
  Av[b * 3 + 0] = S0 / 262.f;
  Av[b * 3 + 1] = S1 / 262.f;
  Av[b * 3 + 2] = S2 / 262.f;
}

// ---------------- dc2 + horizontal 7-min ----------------
__global__ __launch_bounds__(256) void k_dch(const float* __restrict__ x,
                                             const float* __restrict__ Av,
                                             float* __restrict__ dcH) {
  const int y = blockIdx.x, b = blockIdx.y, t = threadIdx.x;
  __shared__ float srow[518];
  const float a0 = Av[b * 3 + 0], a1 = Av[b * 3 + 1], a2 = Av[b * 3 + 2];
  const size_t rowoff = (size_t)b * 3 * 262144 + (size_t)y * 512;
  const float* xr = x + rowoff;
  const float* xg = xr + 262144;
  const float* xb = xg + 262144;
  const float2 r = ((const float2*)xr)[t];
  const float2 g = ((const float2*)xg)[t];
  const float2 bl = ((const float2*)xb)[t];
  srow[3 + 2 * t + 0] = fminf(fminf(r.x / a0, g.x / a1), bl.x / a2);
  srow[3 + 2 * t + 1] = fminf(fminf(r.y / a0, g.y / a1), bl.y / a2);
  if (t < 3) { srow[t] = FINF; srow[515 + t] = FINF; }
  __syncthreads();
  float2 o;
  float m = srow[2 * t];
#pragma unroll
  for (int k = 1; k < 7; ++k) m = fminf(m, srow[2 * t + k]);
  o.x = m;
  m = srow[2 * t + 1];
#pragma unroll
  for (int k = 1; k < 7; ++k) m = fminf(m, srow[2 * t + 1 + k]);
  o.y = m;
  ((float2*)(dcH + ((size_t)b * 512 + y) * 512))[t] = o;
}

// ---------------- final: vertical 7-min + transmission + dehaze + global min/max ----------------
__global__ __launch_bounds__(256) void k_final(const float* __restrict__ x,
                                               const float* __restrict__ dcH,
                                               const float* __restrict__ params,
                                               const float* __restrict__ Av,
                                               float* __restrict__ out,
                                               unsigned* __restrict__ mm) {
  const int y = blockIdx.x, b = blockIdx.y, t = threadIdx.x;
  const float pb = params[b];
  const float a0 = Av[b * 3 + 0], a1 = Av[b * 3 + 1], a2 = Av[b * 3 + 2];
  const float* dH = dcH + (size_t)b * 262144;
  float2 vm = make_float2(FINF, FINF);
#pragma unroll
  for (int dy = -3; dy <= 3; ++dy) {
    const int yy = y + dy;
    if (yy < 0 || yy > 511) continue;
    const float2 v = ((const float2*)(dH + (size_t)yy * 512))[t];
    vm.x = fminf(vm.x, v.x);
    vm.y = fminf(vm.y, v.y);
  }
  const float T0 = fmaxf(1.f - pb * vm.x, 0.01f);
  const float T1 = fmaxf(1.f - pb * vm.y, 0.01f);
  const size_t rowoff = (size_t)b * 3 * 262144 + (size_t)y * 512;
  float lmin = FINF, lmax = -FINF;
#pragma unroll
  for (int c = 0; c < 3; ++c) {
    const float a = (c == 0) ? a0 : ((c == 1) ? a1 : a2);
    const float2 xv = ((const float2*)(x + rowoff + (size_t)c * 262144))[t];
    const float o0 = (xv.x - a) / T0 + a;
    const float o1 = (xv.y - a) / T1 + a;
    lmin = fminf(lmin, fminf(o0, o1));
    lmax = fmaxf(lmax, fmaxf(o0, o1));
    ((float2*)(out + rowoff + (size_t)c * 262144))[t] = make_float2(o0, o1);
  }
  __shared__ float red[256];
  red[t] = lmin; __syncthreads();
  for (int off = 128; off > 0; off >>= 1) { if (t < off) red[t] = fminf(red[t], red[t + off]); __syncthreads(); }
  if (t == 0) atomicMin(&mm[0], mapf(red[0]));
  __syncthreads();
  red[t] = lmax; __syncthreads();
  for (int off = 128; off > 0; off >>= 1) { if (t < off) red[t] = fmaxf(red[t], red[t + off]); __syncthreads(); }
  if (t == 0) atomicMax(&mm[1], mapf(red[0]));
}

// ---------------- global normalize ----------------
__global__ void k_norm(float* __restrict__ out, const unsigned* __restrict__ mm) {
  const float mn = unmapf(mm[0]);
  const float mx = unmapf(mm[1]);
  const float sc = 1.f / (mx - mn);
  const int total4 = 16 * 3 * 262144 / 4;
  for (int i = blockIdx.x * 256 + threadIdx.x; i < total4; i += gridDim.x * 256) {
    float4 v = ((float4*)out)[i];
    v.x = (v.x - mn) * sc;
    v.y = (v.y - mn) * sc;
    v.z = (v.z - mn) * sc;
    v.w = (v.w - mn) * sc;
    ((float4*)out)[i] = v;
  }
}

extern "C" void kernel_launch(void* const* d_in, const int* in_sizes, int n_in,
                              void* d_out, int out_size, void* d_ws, size_t ws_size,
                              hipStream_t stream) {
  const float* x   = (const float*)d_in[0];
  const float* lat = (const float*)d_in[1];
  const float* w1  = (const float*)d_in[2];
  const float* b1  = (const float*)d_in[3];
  const float* w2  = (const float*)d_in[4];
  const float* b2  = (const float*)d_in[5];
  const float* w3  = (const float*)d_in[6];
  const float* b3  = (const float*)d_in[7];
  float* out = (float*)d_out;

  char* ws = (char*)d_ws;
  size_t off = 0;
  auto alloc = [&](size_t sz) -> void* {
    off = (off + 255) & ~(size_t)255;
    void* p = ws + off;
    off += sz;
    return p;
  };
  // dcH (16 MB) is used only AFTER the conv path finishes -> alias h1part onto it.
  float*    dcH   = (float*)alloc((size_t)16 * 512 * 512 * sizeof(float));
  float*    h1p   = dcH;  // 8 ksplit partials = 8*524288 floats = 16 MB, same region
  float*    h1    = (float*)alloc(524288 * sizeof(float));
  float*    wt    = (float*)alloc(294912 * sizeof(float));
  float*    paramsp = (float*)alloc(16 * sizeof(float));
  unsigned* hist  = (unsigned*)alloc(16 * 4096 * sizeof(unsigned));
  int*      Bbin  = (int*)alloc(16 * sizeof(int));
  int*      rneed = (int*)alloc(16 * sizeof(int));
  int*      cnt   = (int*)alloc(16 * sizeof(int));
  float*    bsums = (float*)alloc(16 * 32 * 3 * sizeof(float));
  float*    candv = (float*)alloc(16 * 4096 * sizeof(float));
  int*      candi = (int*)alloc(16 * 4096 * sizeof(int));
  float*    Av    = (float*)alloc(16 * 3 * sizeof(float));
  unsigned* mm    = (unsigned*)alloc(2 * sizeof(unsigned));

  k_init<<<256, 256, 0, stream>>>(hist, cnt, mm);
  k_wt<<<1152, 256, 0, stream>>>(w1, wt);
  k_conv1<<<dim3(16, 16, 8), 256, 0, stream>>>(lat, wt, h1p);
  k_combine<<<512, 256, 0, stream>>>(h1p, h1, b1);
  k_conv2<<<16, 256, 0, stream>>>(h1, w2, b2, w3, b3, paramsp);
  k_hist<<<dim3(32, 16), 256, 0, stream>>>(x, hist);
  k_scan<<<16, 256, 0, stream>>>(hist, Bbin, rneed);
  k_collect<<<dim3(32, 16), 256, 0, stream>>>(x, Bbin, cnt, candv, candi, bsums);
  k_finalA<<<16, 64, 0, stream>>>(x, bsums, cnt, rneed, candv, candi, Av);
  k_dch<<<dim3(512, 16), 256, 0, stream>>>(x, Av, dcH);
  k_final<<<dim3(512, 16), 256, 0, stream>>>(x, dcH, paramsp, Av, out, mm);
  k_norm<<<4096, 256, 0, stream>>>(out, mm);
}

// Round 3
// 205.728 us; speedup vs baseline: 2.5574x; 1.7913x over previous
//
#include <hip/hip_runtime.h>
#include <math.h>

#define FINF 3.0e38f

// ---------------- init small scratch ----------------
__global__ void k_init(unsigned* __restrict__ hist, int* __restrict__ cnt) {
  int i = blockIdx.x * 256 + threadIdx.x;
  if (i < 16 * 4096) hist[i] = 0u;
  if (i < 16) cnt[i] = 0;
}

// ---------------- transpose W1 (128,256,3,3) -> wt[ic][tap][oc] ----------------
__global__ void k_wt(const float* __restrict__ w1, float* __restrict__ wt) {
  const int idx = blockIdx.x * 256 + threadIdx.x;  // 294912 = 256*9*128
  if (idx >= 294912) return;
  const int oc = idx & 127;
  const int r = idx >> 7;
  const int tap = r % 9;
  const int ic = r / 9;
  wt[idx] = w1[((size_t)oc * 256 + ic) * 9 + tap];
}

// ---------------- conv1: latent(16,256,32,32) * W1 s2 p1 -> 8 ksplit partials ----------------
// grid (16 b, 16 ocg, 8 ks), block 256 (one output pixel each), 8 oc per thread, 32 ic per block
__global__ __launch_bounds__(256) void k_conv1(const float* __restrict__ lat,
                                               const float* __restrict__ wt,
                                               float* __restrict__ h1part) {
  const int b = blockIdx.x;
  const int ocg = blockIdx.y;
  const int ks = blockIdx.z;
  const int t = threadIdx.x;
  const int oy = t >> 4, ox = t & 15;
  __shared__ float sIn[4 * 1024];  // 4 channels x 32x32 = 16 KB
  float acc[8];
#pragma unroll
  for (int j = 0; j < 8; ++j) acc[j] = 0.f;
  const int ocb = ocg * 8;
  const int icb = ks * 32;
#pragma unroll 1
  for (int cc = 0; cc < 8; ++cc) {
    const int ic0 = icb + cc * 4;
    const float4* src = (const float4*)lat + ((size_t)b * 256 + ic0) * 256;
    __syncthreads();
#pragma unroll
    for (int ch = 0; ch < 4; ++ch) ((float4*)sIn)[ch * 256 + t] = src[ch * 256 + t];
    __syncthreads();
#pragma unroll
    for (int ic = 0; ic < 4; ++ic) {
      const float* ib = sIn + ic * 1024;
      const float* wp = wt + (size_t)(ic0 + ic) * 9 * 128 + ocb;
#pragma unroll
      for (int ky = 0; ky < 3; ++ky) {
        const int iy = 2 * oy - 1 + ky;
        if (iy < 0) continue;
#pragma unroll
        for (int kx = 0; kx < 3; ++kx) {
          const int ix = 2 * ox - 1 + kx;
          if (ix < 0) continue;
          const float v = ib[iy * 32 + ix];
          const float* w8 = wp + (ky * 3 + kx) * 128;
          const float4 wa = *(const float4*)(w8);
          const float4 wb = *(const float4*)(w8 + 4);
          acc[0] = fmaf(wa.x, v, acc[0]);
          acc[1] = fmaf(wa.y, v, acc[1]);
          acc[2] = fmaf(wa.z, v, acc[2]);
          acc[3] = fmaf(wa.w, v, acc[3]);
          acc[4] = fmaf(wb.x, v, acc[4]);
          acc[5] = fmaf(wb.y, v, acc[5]);
          acc[6] = fmaf(wb.z, v, acc[6]);
          acc[7] = fmaf(wb.w, v, acc[7]);
        }
      }
    }
  }
  float* dst = h1part + (size_t)ks * 524288 + ((size_t)b * 128 + ocb) * 256 + t;
#pragma unroll
  for (int j = 0; j < 8; ++j) dst[j * 256] = acc[j];
}

// ---------------- combine 8 ksplit partials + bias + leaky ----------------
__global__ void k_combine(const float* __restrict__ h1p, float* __restrict__ h1,
                          const float* __restrict__ b1) {
  const int i = blockIdx.x * 256 + threadIdx.x;  // float4 index, 131072 total
  const float4* p = (const float4*)h1p;
  float4 a = p[i];
#pragma unroll
  for (int ks = 1; ks < 8; ++ks) {
    const float4 q = p[(size_t)ks * 131072 + i];
    a.x += q.x; a.y += q.y; a.z += q.z; a.w += q.w;
  }
  const int oc = (i >> 6) & 127;
  const float bias = b1[oc];
  float s;
  s = a.x + bias; a.x = s >= 0.f ? s : 0.02f * s;
  s = a.y + bias; a.y = s >= 0.f ? s : 0.02f * s;
  s = a.z + bias; a.z = s >= 0.f ? s : 0.02f * s;
  s = a.w + bias; a.w = s >= 0.f ? s : 0.02f * s;
  ((float4*)h1)[i] = a;
}

// ---------------- conv2 + mean + 1x1 conv + tanh -> params[b] ----------------
__global__ __launch_bounds__(256) void k_conv2(const float* __restrict__ h1,
                                               const float* __restrict__ w2,
                                               const float* __restrict__ b2,
                                               const float* __restrict__ w3,
                                               const float* __restrict__ b3,
                                               float* __restrict__ params) {
  const int b = blockIdx.x;
  const int t = threadIdx.x;
  __shared__ float sW[1152];
  __shared__ float red[256];
  for (int i = t; i < 1152; i += 256) sW[i] = w2[i];
  __syncthreads();
  const int pix = t >> 2, icq = t & 3;
  const int oy = pix >> 3, ox = pix & 7;
  const float* hb = h1 + (size_t)b * 128 * 256;
  float s = 0.f;
  for (int ic = icq * 32; ic < icq * 32 + 32; ++ic) {
    const float* hp = hb + ic * 256;
#pragma unroll
    for (int ky = 0; ky < 3; ++ky) {
      const int iy = 2 * oy - 1 + ky;
      if (iy < 0) continue;
#pragma unroll
      for (int kx = 0; kx < 3; ++kx) {
        const int ix = 2 * ox - 1 + kx;
        if (ix < 0) continue;
        s += sW[ic * 9 + ky * 3 + kx] * hp[iy * 16 + ix];
      }
    }
  }
  red[t] = s;
  __syncthreads();
  for (int off = 128; off > 0; off >>= 1) {
    if (t < off) red[t] += red[t + off];
    __syncthreads();
  }
  if (t == 0) {
    const float mean = red[0] / 64.f + b2[0];
    const float h = w3[0] * mean + b3[0];
    params[b] = tanhf(h) * 0.5f + 0.5f;
  }
}

// ---------------- histogram of dark channel ----------------
__global__ __launch_bounds__(256) void k_hist(const float* __restrict__ x,
                                              unsigned* __restrict__ ghist) {
  const int b = blockIdx.y, blk = blockIdx.x, t = threadIdx.x;
  __shared__ unsigned lh[4096];
  for (int i = t; i < 4096; i += 256) lh[i] = 0u;
  __syncthreads();
  const float* xr = x + (size_t)b * 3 * 262144;
  const float* xg = xr + 262144;
  const float* xb = xg + 262144;
  const int f0 = blk * 2048;
#pragma unroll
  for (int i = 0; i < 8; ++i) {
    const int f4 = f0 + t + i * 256;
    const float4 r = ((const float4*)xr)[f4];
    const float4 g = ((const float4*)xg)[f4];
    const float4 bl = ((const float4*)xb)[f4];
    float d;
    d = fminf(fminf(r.x, g.x), bl.x); atomicAdd(&lh[min(4095, (int)(d * 4096.f))], 1u);
    d = fminf(fminf(r.y, g.y), bl.y); atomicAdd(&lh[min(4095, (int)(d * 4096.f))], 1u);
    d = fminf(fminf(r.z, g.z), bl.z); atomicAdd(&lh[min(4095, (int)(d * 4096.f))], 1u);
    d = fminf(fminf(r.w, g.w), bl.w); atomicAdd(&lh[min(4095, (int)(d * 4096.f))], 1u);
  }
  __syncthreads();
  for (int i = t; i < 4096; i += 256)
    if (lh[i]) atomicAdd(&ghist[b * 4096 + i], lh[i]);
}

// ---------------- suffix scan from top to find threshold bin ----------------
__global__ __launch_bounds__(256) void k_scan(const unsigned* __restrict__ ghist,
                                              int* __restrict__ Bbin, int* __restrict__ rneed) {
  const int b = blockIdx.x, t = threadIdx.x;
  __shared__ unsigned h[4096];
  __shared__ unsigned csum[256];
  for (int i = t; i < 4096; i += 256) h[i] = ghist[b * 4096 + i];
  __syncthreads();
  const int top = 4095 - 16 * t;
  unsigned s = 0;
#pragma unroll
  for (int k = 0; k < 16; ++k) s += h[top - k];
  csum[t] = s;
  __syncthreads();
  for (int off = 1; off < 256; off <<= 1) {
    const unsigned add = (t >= off) ? csum[t - off] : 0u;
    __syncthreads();
    csum[t] += add;
    __syncthreads();
  }
  const unsigned incl = csum[t];
  const unsigned before = incl - s;
  if (before < 262u && incl >= 262u) {
    unsigned cum = before;
    for (int k = 0; k < 16; ++k) {
      const unsigned c = h[top - k];
      if (cum + c >= 262u) { Bbin[b] = top - k; rneed[b] = (int)(262u - cum); break; }
      cum += c;
    }
  }
}

// ---------------- collect: sums above threshold bin + boundary candidates ----------------
__global__ __launch_bounds__(256) void k_collect(const float* __restrict__ x,
                                                 const int* __restrict__ Bbin,
                                                 int* __restrict__ cnt,
                                                 float* __restrict__ candv,
                                                 int* __restrict__ candi,
                                                 float* __restrict__ bsums) {
  const int b = blockIdx.y, blk = blockIdx.x, t = threadIdx.x;
  const int B = Bbin[b];
  const float* xr = x + (size_t)b * 3 * 262144;
  const float* xg = xr + 262144;
  const float* xb = xg + 262144;
  const int f0 = blk * 2048;
  float s0 = 0.f, s1 = 0.f, s2 = 0.f;
#pragma unroll
  for (int i = 0; i < 8; ++i) {
    const int f4 = f0 + t + i * 256;
    const float4 r = ((const float4*)xr)[f4];
    const float4 g = ((const float4*)xg)[f4];
    const float4 bl = ((const float4*)xb)[f4];
    const float rv[4] = {r.x, r.y, r.z, r.w};
    const float gv[4] = {g.x, g.y, g.z, g.w};
    const float bv[4] = {bl.x, bl.y, bl.z, bl.w};
#pragma unroll
    for (int j = 0; j < 4; ++j) {
      const float d = fminf(fminf(rv[j], gv[j]), bv[j]);
      const int bin = min(4095, (int)(d * 4096.f));
      if (bin > B) {
        s0 += rv[j]; s1 += gv[j]; s2 += bv[j];
      } else if (bin == B) {
        const int k = atomicAdd(&cnt[b], 1);
        if (k < 4096) { candv[b * 4096 + k] = d; candi[b * 4096 + k] = f4 * 4 + j; }
      }
    }
  }
  __shared__ float red[256];
  red[t] = s0; __syncthreads();
  for (int off = 128; off > 0; off >>= 1) { if (t < off) red[t] += red[t + off]; __syncthreads(); }
  if (t == 0) bsums[((size_t)b * 32 + blk) * 3 + 0] = red[0];
  __syncthreads();
  red[t] = s1; __syncthreads();
  for (int off = 128; off > 0; off >>= 1) { if (t < off) red[t] += red[t + off]; __syncthreads(); }
  if (t == 0) bsums[((size_t)b * 32 + blk) * 3 + 1] = red[0];
  __syncthreads();
  red[t] = s2; __syncthreads();
  for (int off = 128; off > 0; off >>= 1) { if (t < off) red[t] += red[t + off]; __syncthreads(); }
  if (t == 0) bsums[((size_t)b * 32 + blk) * 3 + 2] = red[0];
}

// ---------------- finalize A (deterministic; tie-break value desc, index asc) ----------------
__global__ void k_finalA(const float* __restrict__ x, const float* __restrict__ bsums,
                         const int* __restrict__ cnt, const int* __restrict__ rneed,
                         float* __restrict__ candv, const int* __restrict__ candi,
                         float* __restrict__ Av) {
  const int b = blockIdx.x;
  if (threadIdx.x != 0) return;
  float S0 = 0.f, S1 = 0.f, S2 = 0.f;
  for (int k = 0; k < 32; ++k) {
    S0 += bsums[((size_t)b * 32 + k) * 3 + 0];
    S1 += bsums[((size_t)b * 32 + k) * 3 + 1];
    S2 += bsums[((size_t)b * 32 + k) * 3 + 2];
  }
  const int n = min(cnt[b], 4096);
  const int r = rneed[b];
  const float* xr = x + (size_t)b * 3 * 262144;
  const float* xg = xr + 262144;
  const float* xb = xg + 262144;
  for (int sel = 0; sel < r; ++sel) {
    int best = -1; float bv = -1.f; int bi = 0x7FFFFFFF;
    for (int i = 0; i < n; ++i) {
      const float v = candv[b * 4096 + i];
      const int id = candi[b * 4096 + i];
      if (v > bv || (v == bv && id < bi)) { best = i; bv = v; bi = id; }
    }
    if (best < 0) break;
    candv[b * 4096 + best] = -1.f;
    S0 += xr[bi]; S1 += xg[bi]; S2 += xb[bi];
  }
  Av[b * 3 + 0] = S0 / 262.f;
  Av[b * 3 + 1] = S1 / 262.f;
  Av[b * 3 + 2] = S2 / 262.f;
}

// ---------------- dc2 + horizontal 7-min (XCD-swizzled) ----------------
__global__ __launch_bounds__(256) void k_dch(const float* __restrict__ x,
                                             const float* __restrict__ Av,
                                             float* __restrict__ dcH) {
  // 8192 blocks; chunked XCD swizzle: each XCD gets 2 whole images
  const int lid = blockIdx.y * gridDim.x + blockIdx.x;
  const int swz = (lid & 7) * 1024 + (lid >> 3);
  const int y = swz & 511, b = swz >> 9;
  const int t = threadIdx.x;
  __shared__ float srow[518];
  const float a0 = Av[b * 3 + 0], a1 = Av[b * 3 + 1], a2 = Av[b * 3 + 2];
  const size_t rowoff = (size_t)b * 3 * 262144 + (size_t)y * 512;
  const float* xr = x + rowoff;
  const float* xg = xr + 262144;
  const float* xb = xg + 262144;
  const float2 r = ((const float2*)xr)[t];
  const float2 g = ((const float2*)xg)[t];
  const float2 bl = ((const float2*)xb)[t];
  srow[3 + 2 * t + 0] = fminf(fminf(r.x / a0, g.x / a1), bl.x / a2);
  srow[3 + 2 * t + 1] = fminf(fminf(r.y / a0, g.y / a1), bl.y / a2);
  if (t < 3) { srow[t] = FINF; srow[515 + t] = FINF; }
  __syncthreads();
  float2 o;
  float m = srow[2 * t];
#pragma unroll
  for (int k = 1; k < 7; ++k) m = fminf(m, srow[2 * t + k]);
  o.x = m;
  m = srow[2 * t + 1];
#pragma unroll
  for (int k = 1; k < 7; ++k) m = fminf(m, srow[2 * t + 1 + k]);
  o.y = m;
  ((float2*)(dcH + ((size_t)b * 512 + y) * 512))[t] = o;
}

// ---------------- final: vertical 7-min + transmission + dehaze; per-block minmax partials ----------------
__global__ __launch_bounds__(256) void k_final(const float* __restrict__ x,
                                               const float* __restrict__ dcH,
                                               const float* __restrict__ params,
                                               const float* __restrict__ Av,
                                               float* __restrict__ out,
                                               float2* __restrict__ pmm) {
  const int lid = blockIdx.y * gridDim.x + blockIdx.x;
  const int swz = (lid & 7) * 1024 + (lid >> 3);  // same mapping as k_dch -> dcH is L2-local
  const int y = swz & 511, b = swz >> 9;
  const int t = threadIdx.x;
  const float pb = params[b];
  const float a0 = Av[b * 3 + 0], a1 = Av[b * 3 + 1], a2 = Av[b * 3 + 2];
  const float* dH = dcH + (size_t)b * 262144;
  float2 vm = make_float2(FINF, FINF);
#pragma unroll
  for (int dy = -3; dy <= 3; ++dy) {
    const int yy = y + dy;
    if (yy < 0 || yy > 511) continue;
    const float2 v = ((const float2*)(dH + (size_t)yy * 512))[t];
    vm.x = fminf(vm.x, v.x);
    vm.y = fminf(vm.y, v.y);
  }
  const float T0 = fmaxf(1.f - pb * vm.x, 0.01f);
  const float T1 = fmaxf(1.f - pb * vm.y, 0.01f);
  const float i0 = 1.f / T0;
  const float i1 = 1.f / T1;
  const size_t rowoff = (size_t)b * 3 * 262144 + (size_t)y * 512;
  float lmin = FINF, lmax = -FINF;
#pragma unroll
  for (int c = 0; c < 3; ++c) {
    const float a = (c == 0) ? a0 : ((c == 1) ? a1 : a2);
    const float2 xv = ((const float2*)(x + rowoff + (size_t)c * 262144))[t];
    const float o0 = fmaf(xv.x - a, i0, a);
    const float o1 = fmaf(xv.y - a, i1, a);
    lmin = fminf(lmin, fminf(o0, o1));
    lmax = fmaxf(lmax, fmaxf(o0, o1));
    ((float2*)(out + rowoff + (size_t)c * 262144))[t] = make_float2(o0, o1);
  }
  __shared__ float red[256];
  red[t] = lmin; __syncthreads();
  for (int off = 128; off > 0; off >>= 1) { if (t < off) red[t] = fminf(red[t], red[t + off]); __syncthreads(); }
  const float bmin = red[0];
  __syncthreads();
  red[t] = lmax; __syncthreads();
  for (int off = 128; off > 0; off >>= 1) { if (t < off) red[t] = fmaxf(red[t], red[t + off]); __syncthreads(); }
  if (t == 0) pmm[lid] = make_float2(bmin, red[0]);
}

// ---------------- reduce 8192 per-block partials -> mm (no atomics) ----------------
__global__ __launch_bounds__(256) void k_redmm(const float2* __restrict__ pmm,
                                               float* __restrict__ mm) {
  const int t = threadIdx.x;
  float mn = FINF, mx = -FINF;
  for (int i = t; i < 8192; i += 256) {
    const float2 v = pmm[i];
    mn = fminf(mn, v.x);
    mx = fmaxf(mx, v.y);
  }
  __shared__ float rmn[256], rmx[256];
  rmn[t] = mn; rmx[t] = mx;
  __syncthreads();
  for (int off = 128; off > 0; off >>= 1) {
    if (t < off) {
      rmn[t] = fminf(rmn[t], rmn[t + off]);
      rmx[t] = fmaxf(rmx[t], rmx[t + off]);
    }
    __syncthreads();
  }
  if (t == 0) { mm[0] = rmn[0]; mm[1] = rmx[0]; }
}

// ---------------- global normalize ----------------
__global__ void k_norm(float* __restrict__ out, const float* __restrict__ mm) {
  const float mn = mm[0];
  const float sc = 1.f / (mm[1] - mn);
  const int total4 = 16 * 3 * 262144 / 4;
  for (int i = blockIdx.x * 256 + threadIdx.x; i < total4; i += gridDim.x * 256) {
    float4 v = ((float4*)out)[i];
    v.x = (v.x - mn) * sc;
    v.y = (v.y - mn) * sc;
    v.z = (v.z - mn) * sc;
    v.w = (v.w - mn) * sc;
    ((float4*)out)[i] = v;
  }
}

extern "C" void kernel_launch(void* const* d_in, const int* in_sizes, int n_in,
                              void* d_out, int out_size, void* d_ws, size_t ws_size,
                              hipStream_t stream) {
  const float* x   = (const float*)d_in[0];
  const float* lat = (const float*)d_in[1];
  const float* w1  = (const float*)d_in[2];
  const float* b1  = (const float*)d_in[3];
  const float* w2  = (const float*)d_in[4];
  const float* b2  = (const float*)d_in[5];
  const float* w3  = (const float*)d_in[6];
  const float* b3  = (const float*)d_in[7];
  float* out = (float*)d_out;

  char* ws = (char*)d_ws;
  size_t off = 0;
  auto alloc = [&](size_t sz) -> void* {
    off = (off + 255) & ~(size_t)255;
    void* p = ws + off;
    off += sz;
    return p;
  };
  // dcH (16 MB) is used only AFTER the conv path finishes -> alias h1part onto it.
  float*    dcH   = (float*)alloc((size_t)16 * 512 * 512 * sizeof(float));
  float*    h1p   = dcH;  // 8 ksplit partials = 8*524288 floats = 16 MB, same region
  float*    h1    = (float*)alloc(524288 * sizeof(float));
  float*    wt    = (float*)alloc(294912 * sizeof(float));
  float*    paramsp = (float*)alloc(16 * sizeof(float));
  unsigned* hist  = (unsigned*)alloc(16 * 4096 * sizeof(unsigned));
  int*      Bbin  = (int*)alloc(16 * sizeof(int));
  int*      rneed = (int*)alloc(16 * sizeof(int));
  int*      cnt   = (int*)alloc(16 * sizeof(int));
  float*    bsums = (float*)alloc(16 * 32 * 3 * sizeof(float));
  float*    candv = (float*)alloc(16 * 4096 * sizeof(float));
  int*      candi = (int*)alloc(16 * 4096 * sizeof(int));
  float*    Av    = (float*)alloc(16 * 3 * sizeof(float));
  float2*   pmm   = (float2*)alloc(8192 * sizeof(float2));
  float*    mm    = (float*)alloc(2 * sizeof(float));

  k_init<<<256, 256, 0, stream>>>(hist, cnt);
  k_wt<<<1152, 256, 0, stream>>>(w1, wt);
  k_conv1<<<dim3(16, 16, 8), 256, 0, stream>>>(lat, wt, h1p);
  k_combine<<<512, 256, 0, stream>>>(h1p, h1, b1);
  k_conv2<<<16, 256, 0, stream>>>(h1, w2, b2, w3, b3, paramsp);
  k_hist<<<dim3(32, 16), 256, 0, stream>>>(x, hist);
  k_scan<<<16, 256, 0, stream>>>(hist, Bbin, rneed);
  k_collect<<<dim3(32, 16), 256, 0, stream>>>(x, Bbin, cnt, candv, candi, bsums);
  k_finalA<<<16, 64, 0, stream>>>(x, bsums, cnt, rneed, candv, candi, Av);
  k_dch<<<dim3(512, 16), 256, 0, stream>>>(x, Av, dcH);
  k_final<<<dim3(512, 16), 256, 0, stream>>>(x, dcH, paramsp, Av, out, pmm);
  k_redmm<<<1, 256, 0, stream>>>(pmm, mm);
  k_norm<<<4096, 256, 0, stream>>>(out, mm);
}